// Round 1
// baseline (1816.926 us; speedup 1.0000x reference)
//
#include <hip/hip_runtime.h>
#include <hip/hip_bf16.h>
#include <math.h>

// ---------------------------------------------------------------------------
// UHG GNN forward:
//   h1 = normalize(relu(x @ W_in + b_in));            mq1 = mink(h1,h1) per node
//   agg1 = segment_sum(h1[row] * exp(-uhg_dist), col)
//   h2 = normalize(relu(agg1 @ W1 + b1));             mq2
//   agg2 = segment_sum(h2[row] * exp(-uhg_dist), col)
//   h3 = normalize(relu(agg2 @ W2 + b2))
//   out = sigmoid(relu(h3 @ Wc1 + bc1) @ Wc2 + bc2)
// ---------------------------------------------------------------------------

// Fused GEMM + bias + relu + row-normalize (+ optional mink(h,h) output).
// Block: 256 threads. Each thread: 8 rows x 1 col. Block tile: RPB rows x M cols.
// A is [N,K] row-major, W is [K,M] row-major, H is [N,M].
template<int K, int M, bool WANT_MQ>
__global__ __launch_bounds__(256) void gemm_relu_norm(
    const float* __restrict__ A, const float* __restrict__ W,
    const float* __restrict__ bias, float* __restrict__ H,
    float* __restrict__ mqout, int N)
{
    constexpr int GROUPS = 256 / M;       // row-groups per block
    constexpr int RPB    = GROUPS * 8;    // rows per block (16 for M=128, 32 for M=64)
    constexpr int WPG    = M / 64;        // waves per row-group

    __shared__ float4 As[RPB * K / 4];
    __shared__ float  red[4][8];          // per-wave row-norm partials

    const int tid  = threadIdx.x;
    const int col  = tid % M;
    const int grp  = tid / M;
    const int row0 = blockIdx.x * RPB;

    // stage A tile (coalesced float4)
    const float4* Ag = (const float4*)(A + (size_t)row0 * K);
    #pragma unroll
    for (int i = 0; i < RPB * K / 4 / 256; ++i)
        As[tid + i * 256] = Ag[tid + i * 256];
    __syncthreads();

    float acc[8];
    #pragma unroll
    for (int r = 0; r < 8; ++r) acc[r] = 0.f;

    for (int k4 = 0; k4 < K / 4; ++k4) {
        const int k = k4 * 4;
        const float w0 = W[(k + 0) * M + col];
        const float w1 = W[(k + 1) * M + col];
        const float w2 = W[(k + 2) * M + col];
        const float w3 = W[(k + 3) * M + col];
        #pragma unroll
        for (int r = 0; r < 8; ++r) {
            const float4 a = As[(grp * 8 + r) * (K / 4) + k4];  // LDS broadcast
            acc[r] += a.x * w0 + a.y * w1 + a.z * w2 + a.w * w3;
        }
    }

    const float bv   = bias[col];
    const int   wave = tid >> 6;
    const int   lane = tid & 63;

    float val[8], v2s[8];
    #pragma unroll
    for (int r = 0; r < 8; ++r) {
        val[r] = fmaxf(acc[r] + bv, 0.f);
        float v2 = val[r] * val[r];
        #pragma unroll
        for (int off = 1; off < 64; off <<= 1) v2 += __shfl_xor(v2, off);
        v2s[r] = v2;
    }
    if (lane == 0) {
        #pragma unroll
        for (int r = 0; r < 8; ++r) red[wave][r] = v2s[r];
    }
    __syncthreads();

    const int wbase = grp * WPG;
    #pragma unroll
    for (int r = 0; r < 8; ++r) {
        float ss = 0.f;
        #pragma unroll
        for (int w = 0; w < WPG; ++w) ss += red[wbase + w][r];
        const float nrm = sqrtf(ss) + 1e-9f;
        const float inv = 1.f / nrm;
        const float hv  = val[r] * inv;
        const int   row = row0 + grp * 8 + r;
        if (row < N) {
            H[(size_t)row * M + col] = hv;
            if (WANT_MQ && col == M - 1) {
                // mink(h,h) = sum(h^2) - 2*h_last^2
                mqout[row] = ss * inv * inv - 2.f * hv * hv;
            }
        }
    }
}

// Wave-per-edge message pass for D=128.
// w = exp(-sqrt(max(0, 1 - mink(a,b)^2/(mq_r*mq_c + eps)))); agg[col] += h[row]*w
__global__ __launch_bounds__(256) void message_pass(
    const float* __restrict__ h, const float* __restrict__ mq,
    const int* __restrict__ row, const int* __restrict__ col,
    float* __restrict__ agg, int E)
{
    const int wid  = (int)((blockIdx.x * (unsigned)blockDim.x + threadIdx.x) >> 6);
    const int lane = threadIdx.x & 63;
    if (wid >= E) return;

    const int r = row[wid];
    const int c = col[wid];

    const float a0 = h[(size_t)r * 128 + lane];
    const float a1 = h[(size_t)r * 128 + 64 + lane];
    const float b0 = h[(size_t)c * 128 + lane];
    const float b1 = h[(size_t)c * 128 + 64 + lane];

    // mink(a,b): + on coords 0..126, - on coord 127 (lane 63's second element)
    float p = a0 * b0 + ((lane == 63) ? -a1 * b1 : a1 * b1);
    #pragma unroll
    for (int off = 1; off < 64; off <<= 1) p += __shfl_xor(p, off);

    const float denom = mq[r] * mq[c] + 1e-9f;
    float q = 1.f - (p * p) / denom;
    q = fmaxf(q, 0.f);
    const float w = expf(-sqrtf(q));

    atomicAdd(&agg[(size_t)c * 128 + lane],      a0 * w);
    atomicAdd(&agg[(size_t)c * 128 + 64 + lane], a1 * w);
}

// Final classifier: out = sigmoid(relu(h3 @ Wc1 + bc1) @ Wc2 + bc2), h3 is [N,64]
__global__ __launch_bounds__(256) void classifier_kernel(
    const float* __restrict__ h3, const float* __restrict__ Wc1,
    const float* __restrict__ bc1, const float* __restrict__ Wc2,
    const float* __restrict__ bc2, float* __restrict__ out, int N)
{
    __shared__ float w1[64 * 32];
    __shared__ float w2[32];
    __shared__ float b1s[32];

    const int tid = threadIdx.x;
    for (int i = tid; i < 64 * 32; i += 256) w1[i] = Wc1[i];
    if (tid < 32) { w2[tid] = Wc2[tid]; b1s[tid] = bc1[tid]; }
    __syncthreads();

    const int n = blockIdx.x * 256 + tid;
    if (n >= N) return;

    float t1[32];
    #pragma unroll
    for (int c = 0; c < 32; ++c) t1[c] = b1s[c];

    const float4* hrow = (const float4*)(h3 + (size_t)n * 64);
    #pragma unroll
    for (int k4 = 0; k4 < 16; ++k4) {
        const float4 hv = hrow[k4];
        const int k = k4 * 4;
        #pragma unroll
        for (int c = 0; c < 32; ++c) {
            t1[c] += hv.x * w1[(k + 0) * 32 + c] + hv.y * w1[(k + 1) * 32 + c]
                   + hv.z * w1[(k + 2) * 32 + c] + hv.w * w1[(k + 3) * 32 + c];
        }
    }

    float z = bc2[0];
    #pragma unroll
    for (int c = 0; c < 32; ++c) z += fmaxf(t1[c], 0.f) * w2[c];
    out[n] = 1.f / (1.f + expf(-z));
}

extern "C" void kernel_launch(void* const* d_in, const int* in_sizes, int n_in,
                              void* d_out, int out_size, void* d_ws, size_t ws_size,
                              hipStream_t stream)
{
    const float* x    = (const float*)d_in[0];
    const int*   ei   = (const int*)  d_in[1];
    const float* W_in = (const float*)d_in[2];
    const float* b_in = (const float*)d_in[3];
    const float* W1   = (const float*)d_in[4];
    const float* b1   = (const float*)d_in[5];
    const float* W2   = (const float*)d_in[6];
    const float* b2   = (const float*)d_in[7];
    const float* Wc1  = (const float*)d_in[8];
    const float* bc1  = (const float*)d_in[9];
    const float* Wc2  = (const float*)d_in[10];
    const float* bc2  = (const float*)d_in[11];
    float* out = (float*)d_out;

    const int N = in_sizes[0] / 256;   // 100000
    const int E = in_sizes[1] / 2;     // 1600000
    const int* row = ei;
    const int* col = ei + E;

    float* bufA = (float*)d_ws;                   // [N,128] h buffer
    float* bufB = bufA + (size_t)N * 128;         // [N,128] agg buffer
    float* mq   = bufB + (size_t)N * 128;         // [N] mink(h,h)

    const int mp_blocks = (E + 3) / 4;            // 4 edges (waves) per block

    // Layer 1: h1 = norm(relu(x @ W_in + b_in)), mq1
    gemm_relu_norm<256, 128, true><<<N / 16, 256, 0, stream>>>(x, W_in, b_in, bufA, mq, N);
    hipMemsetAsync(bufB, 0, (size_t)N * 128 * sizeof(float), stream);
    message_pass<<<mp_blocks, 256, 0, stream>>>(bufA, mq, row, col, bufB, E);

    // Layer 2: h2 = norm(relu(agg1 @ W1 + b1)), mq2
    gemm_relu_norm<128, 128, true><<<N / 16, 256, 0, stream>>>(bufB, W1, b1, bufA, mq, N);
    hipMemsetAsync(bufB, 0, (size_t)N * 128 * sizeof(float), stream);
    message_pass<<<mp_blocks, 256, 0, stream>>>(bufA, mq, row, col, bufB, E);

    // Layer 3: h3 = norm(relu(agg2 @ W2 + b2))  [N,64]
    gemm_relu_norm<128, 64, false><<<N / 32, 256, 0, stream>>>(bufB, W2, b2, bufA, nullptr, N);

    // Classifier head
    classifier_kernel<<<(N + 255) / 256, 256, 0, stream>>>(bufA, Wc1, bc1, Wc2, bc2, out, N);
}

// Round 2
// 925.492 us; speedup vs baseline: 1.9632x; 1.9632x over previous
//
#include <hip/hip_runtime.h>
#include <hip/hip_bf16.h>
#include <math.h>

// ---------------------------------------------------------------------------
// UHG GNN forward:
//   h1 = normalize(relu(x @ W_in + b_in));            mq1 = mink(h1,h1) per node
//   agg1 = segment_sum(h1[row] * exp(-uhg_dist), col)
//   h2 = normalize(relu(agg1 @ W1 + b1));             mq2
//   agg2 = segment_sum(h2[row] * exp(-uhg_dist), col)
//   h3 = normalize(relu(agg2 @ W2 + b2))
//   out = sigmoid(relu(h3 @ Wc1 + bc1) @ Wc2 + bc2)
//
// R2: message pass rewritten CSR-style (built on-device every launch):
//   - edges grouped by col; one wave per destination node
//   - h[col]/mq[col] read once per node (halves gather traffic)
//   - register accumulation, single 512B store per node (no atomics,
//     no memset of agg buffer) -> WRITE_SIZE 800MB -> ~51MB per pass
// ---------------------------------------------------------------------------

// Fused GEMM + bias + relu + row-normalize (+ optional mink(h,h) output).
template<int K, int M, bool WANT_MQ>
__global__ __launch_bounds__(256) void gemm_relu_norm(
    const float* __restrict__ A, const float* __restrict__ W,
    const float* __restrict__ bias, float* __restrict__ H,
    float* __restrict__ mqout, int N)
{
    constexpr int GROUPS = 256 / M;       // row-groups per block
    constexpr int RPB    = GROUPS * 8;    // rows per block
    constexpr int WPG    = M / 64;        // waves per row-group

    __shared__ float4 As[RPB * K / 4];
    __shared__ float  red[4][8];

    const int tid  = threadIdx.x;
    const int col  = tid % M;
    const int grp  = tid / M;
    const int row0 = blockIdx.x * RPB;

    const float4* Ag = (const float4*)(A + (size_t)row0 * K);
    #pragma unroll
    for (int i = 0; i < RPB * K / 4 / 256; ++i)
        As[tid + i * 256] = Ag[tid + i * 256];
    __syncthreads();

    float acc[8];
    #pragma unroll
    for (int r = 0; r < 8; ++r) acc[r] = 0.f;

    for (int k4 = 0; k4 < K / 4; ++k4) {
        const int k = k4 * 4;
        const float w0 = W[(k + 0) * M + col];
        const float w1 = W[(k + 1) * M + col];
        const float w2 = W[(k + 2) * M + col];
        const float w3 = W[(k + 3) * M + col];
        #pragma unroll
        for (int r = 0; r < 8; ++r) {
            const float4 a = As[(grp * 8 + r) * (K / 4) + k4];  // LDS broadcast
            acc[r] += a.x * w0 + a.y * w1 + a.z * w2 + a.w * w3;
        }
    }

    const float bv   = bias[col];
    const int   wave = tid >> 6;
    const int   lane = tid & 63;

    float val[8], v2s[8];
    #pragma unroll
    for (int r = 0; r < 8; ++r) {
        val[r] = fmaxf(acc[r] + bv, 0.f);
        float v2 = val[r] * val[r];
        #pragma unroll
        for (int off = 1; off < 64; off <<= 1) v2 += __shfl_xor(v2, off);
        v2s[r] = v2;
    }
    if (lane == 0) {
        #pragma unroll
        for (int r = 0; r < 8; ++r) red[wave][r] = v2s[r];
    }
    __syncthreads();

    const int wbase = grp * WPG;
    #pragma unroll
    for (int r = 0; r < 8; ++r) {
        float ss = 0.f;
        #pragma unroll
        for (int w = 0; w < WPG; ++w) ss += red[wbase + w][r];
        const float nrm = sqrtf(ss) + 1e-9f;
        const float inv = 1.f / nrm;
        const float hv  = val[r] * inv;
        const int   row = row0 + grp * 8 + r;
        if (row < N) {
            H[(size_t)row * M + col] = hv;
            if (WANT_MQ && col == M - 1) {
                mqout[row] = ss * inv * inv - 2.f * hv * hv;  // mink(h,h)
            }
        }
    }
}

// ------------------------- CSR build -------------------------

__global__ void hist_kernel(const int* __restrict__ col, int* __restrict__ cnt, int E) {
    const int i = blockIdx.x * blockDim.x + threadIdx.x;
    if (i < E) atomicAdd(&cnt[col[i]], 1);
}

#define SCAN_TPB 256
#define SCAN_VPT 4   // 1024 elems per block

__global__ void scan1_kernel(const int* __restrict__ cnt, int* __restrict__ base,
                             int* __restrict__ bsum, int N) {
    __shared__ int s[SCAN_TPB];
    const int t  = threadIdx.x;
    const int i0 = blockIdx.x * (SCAN_TPB * SCAN_VPT) + t * SCAN_VPT;
    int v[SCAN_VPT]; int tot = 0;
    #pragma unroll
    for (int j = 0; j < SCAN_VPT; ++j) {
        v[j] = (i0 + j < N) ? cnt[i0 + j] : 0;
        tot += v[j];
    }
    s[t] = tot;
    __syncthreads();
    for (int off = 1; off < SCAN_TPB; off <<= 1) {
        const int x = (t >= off) ? s[t - off] : 0;
        __syncthreads();
        s[t] += x;
        __syncthreads();
    }
    const int excl = s[t] - tot;
    if (t == SCAN_TPB - 1) bsum[blockIdx.x] = s[SCAN_TPB - 1];
    int run = excl;
    #pragma unroll
    for (int j = 0; j < SCAN_VPT; ++j) {
        if (i0 + j < N) base[i0 + j] = run;
        run += v[j];
    }
}

__global__ void scan2_kernel(int* __restrict__ bsum, int nb) {
    __shared__ int s[SCAN_TPB];
    const int t = threadIdx.x;
    const int v = (t < nb) ? bsum[t] : 0;
    s[t] = v;
    __syncthreads();
    for (int off = 1; off < SCAN_TPB; off <<= 1) {
        const int x = (t >= off) ? s[t - off] : 0;
        __syncthreads();
        s[t] += x;
        __syncthreads();
    }
    if (t < nb) bsum[t] = s[t] - v;   // exclusive
}

__global__ void scan3_kernel(int* __restrict__ base, const int* __restrict__ bsum,
                             int* __restrict__ cursor, int N) {
    const int i = blockIdx.x * blockDim.x + threadIdx.x;
    if (i < N) {
        const int v = base[i] + bsum[i / (SCAN_TPB * SCAN_VPT)];
        base[i]   = v;
        cursor[i] = v;
    }
}

__global__ void scatter_kernel(const int* __restrict__ row, const int* __restrict__ col,
                               int* __restrict__ cursor, int* __restrict__ srow, int E) {
    const int i = blockIdx.x * blockDim.x + threadIdx.x;
    if (i < E) {
        const int pos = atomicAdd(&cursor[col[i]], 1);
        srow[pos] = row[i];
    }
}

// ------------------------- CSR message pass -------------------------
// One wave per destination node. Four 16-lane groups, each handling one
// incoming edge at a time (8 h-elems per lane). No atomics.
__global__ __launch_bounds__(256) void message_pass_csr(
    const float* __restrict__ h, const float* __restrict__ mq,
    const int* __restrict__ srow, const int* __restrict__ base,
    const int* __restrict__ cnt, float* __restrict__ agg, int N)
{
    const int node = (int)((blockIdx.x * 256u + threadIdx.x) >> 6);
    if (node >= N) return;
    const int lane = threadIdx.x & 63;
    const int gl   = lane & 15;      // lane within 16-lane group
    const int g    = lane >> 4;      // group 0..3

    const float4* hb = (const float4*)(h + (size_t)node * 128 + gl * 8);
    const float4 b0 = hb[0];
    const float4 b1 = hb[1];
    const float mqc = mq[node];

    const int nb = cnt[node];
    const int st = base[node];

    float4 acc0 = {0.f, 0.f, 0.f, 0.f};
    float4 acc1 = {0.f, 0.f, 0.f, 0.f};

    const int iters = (nb + 3) >> 2;
    for (int t = 0; t < iters; ++t) {
        const int ei  = t * 4 + g;
        const bool act = ei < nb;
        const int e   = st + (act ? ei : 0);
        const int r   = srow[e];
        const float4* ha = (const float4*)(h + (size_t)r * 128 + gl * 8);
        const float4 a0 = ha[0];
        const float4 a1 = ha[1];
        const float mqr = mq[r];

        float p = a0.x*b0.x + a0.y*b0.y + a0.z*b0.z + a0.w*b0.w
                + a1.x*b1.x + a1.y*b1.y + a1.z*b1.z;
        p += (gl == 15) ? -a1.w * b1.w : a1.w * b1.w;   // Minkowski sign on elem 127
        p += __shfl_xor(p, 1);
        p += __shfl_xor(p, 2);
        p += __shfl_xor(p, 4);
        p += __shfl_xor(p, 8);

        const float denom = mqr * mqc + 1e-9f;
        float q = 1.f - (p * p) / denom;
        q = fmaxf(q, 0.f);
        float w = expf(-sqrtf(q));
        w = act ? w : 0.f;

        acc0.x += a0.x*w; acc0.y += a0.y*w; acc0.z += a0.z*w; acc0.w += a0.w*w;
        acc1.x += a1.x*w; acc1.y += a1.y*w; acc1.z += a1.z*w; acc1.w += a1.w*w;
    }

    // sum partials across the 4 groups (same elem slots at lanes gl+16k)
    #pragma unroll
    for (int off = 16; off < 64; off <<= 1) {
        acc0.x += __shfl_xor(acc0.x, off); acc0.y += __shfl_xor(acc0.y, off);
        acc0.z += __shfl_xor(acc0.z, off); acc0.w += __shfl_xor(acc0.w, off);
        acc1.x += __shfl_xor(acc1.x, off); acc1.y += __shfl_xor(acc1.y, off);
        acc1.z += __shfl_xor(acc1.z, off); acc1.w += __shfl_xor(acc1.w, off);
    }
    if (g == 0) {
        float4* out = (float4*)(agg + (size_t)node * 128 + gl * 8);
        out[0] = acc0;
        out[1] = acc1;
    }
}

// ------------------------- fallback atomic message pass -------------------------
__global__ __launch_bounds__(256) void message_pass(
    const float* __restrict__ h, const float* __restrict__ mq,
    const int* __restrict__ row, const int* __restrict__ col,
    float* __restrict__ agg, int E)
{
    const int wid  = (int)((blockIdx.x * (unsigned)blockDim.x + threadIdx.x) >> 6);
    const int lane = threadIdx.x & 63;
    if (wid >= E) return;

    const int r = row[wid];
    const int c = col[wid];

    const float a0 = h[(size_t)r * 128 + lane];
    const float a1 = h[(size_t)r * 128 + 64 + lane];
    const float b0 = h[(size_t)c * 128 + lane];
    const float b1 = h[(size_t)c * 128 + 64 + lane];

    float p = a0 * b0 + ((lane == 63) ? -a1 * b1 : a1 * b1);
    #pragma unroll
    for (int off = 1; off < 64; off <<= 1) p += __shfl_xor(p, off);

    const float denom = mq[r] * mq[c] + 1e-9f;
    float q = 1.f - (p * p) / denom;
    q = fmaxf(q, 0.f);
    const float w = expf(-sqrtf(q));

    atomicAdd(&agg[(size_t)c * 128 + lane],      a0 * w);
    atomicAdd(&agg[(size_t)c * 128 + 64 + lane], a1 * w);
}

// ------------------------- classifier -------------------------
__global__ __launch_bounds__(256) void classifier_kernel(
    const float* __restrict__ h3, const float* __restrict__ Wc1,
    const float* __restrict__ bc1, const float* __restrict__ Wc2,
    const float* __restrict__ bc2, float* __restrict__ out, int N)
{
    __shared__ float w1[64 * 32];
    __shared__ float w2[32];
    __shared__ float b1s[32];

    const int tid = threadIdx.x;
    for (int i = tid; i < 64 * 32; i += 256) w1[i] = Wc1[i];
    if (tid < 32) { w2[tid] = Wc2[tid]; b1s[tid] = bc1[tid]; }
    __syncthreads();

    const int n = blockIdx.x * 256 + tid;
    if (n >= N) return;

    float t1[32];
    #pragma unroll
    for (int c = 0; c < 32; ++c) t1[c] = b1s[c];

    const float4* hrow = (const float4*)(h3 + (size_t)n * 64);
    #pragma unroll
    for (int k4 = 0; k4 < 16; ++k4) {
        const float4 hv = hrow[k4];
        const int k = k4 * 4;
        #pragma unroll
        for (int c = 0; c < 32; ++c) {
            t1[c] += hv.x * w1[(k + 0) * 32 + c] + hv.y * w1[(k + 1) * 32 + c]
                   + hv.z * w1[(k + 2) * 32 + c] + hv.w * w1[(k + 3) * 32 + c];
        }
    }

    float z = bc2[0];
    #pragma unroll
    for (int c = 0; c < 32; ++c) z += fmaxf(t1[c], 0.f) * w2[c];
    out[n] = 1.f / (1.f + expf(-z));
}

extern "C" void kernel_launch(void* const* d_in, const int* in_sizes, int n_in,
                              void* d_out, int out_size, void* d_ws, size_t ws_size,
                              hipStream_t stream)
{
    const float* x    = (const float*)d_in[0];
    const int*   ei   = (const int*)  d_in[1];
    const float* W_in = (const float*)d_in[2];
    const float* b_in = (const float*)d_in[3];
    const float* W1   = (const float*)d_in[4];
    const float* b1   = (const float*)d_in[5];
    const float* W2   = (const float*)d_in[6];
    const float* b2   = (const float*)d_in[7];
    const float* Wc1  = (const float*)d_in[8];
    const float* bc1  = (const float*)d_in[9];
    const float* Wc2  = (const float*)d_in[10];
    const float* bc2  = (const float*)d_in[11];
    float* out = (float*)d_out;

    const int N = in_sizes[0] / 256;   // 100000
    const int E = in_sizes[1] / 2;     // 1600000
    const int* row = ei;
    const int* col = ei + E;

    float* bufA = (float*)d_ws;                   // [N,128]
    float* bufB = bufA + (size_t)N * 128;         // [N,128]
    float* mq   = bufB + (size_t)N * 128;         // [N]
    int*   cnt  = (int*)(mq + N);                 // [N]
    int*   base = cnt + N;                        // [N]
    int*   cur  = base + N;                       // [N]
    int*   bsum = cur + N;                        // [256]
    int*   srow = bsum + 256;                     // [E]

    const size_t need = ((size_t)N * 257 + (size_t)N * 3 + 256 + (size_t)E) * 4;
    const bool use_csr = ws_size >= need;

    const int scan_blk = (N + SCAN_TPB * SCAN_VPT - 1) / (SCAN_TPB * SCAN_VPT);  // 98

    if (use_csr) {
        // ---- build CSR (by col) once; reused by both passes ----
        hipMemsetAsync(cnt, 0, (size_t)N * sizeof(int), stream);
        hist_kernel<<<(E + 255) / 256, 256, 0, stream>>>(col, cnt, E);
        scan1_kernel<<<scan_blk, SCAN_TPB, 0, stream>>>(cnt, base, bsum, N);
        scan2_kernel<<<1, SCAN_TPB, 0, stream>>>(bsum, scan_blk);
        scan3_kernel<<<(N + 255) / 256, 256, 0, stream>>>(base, bsum, cur, N);
        scatter_kernel<<<(E + 255) / 256, 256, 0, stream>>>(row, col, cur, srow, E);
    }

    const int mp_blocks_csr = (N + 3) / 4;
    const int mp_blocks_atm = (E + 3) / 4;

    // Layer 1
    gemm_relu_norm<256, 128, true><<<(N + 15) / 16, 256, 0, stream>>>(x, W_in, b_in, bufA, mq, N);
    if (use_csr) {
        message_pass_csr<<<mp_blocks_csr, 256, 0, stream>>>(bufA, mq, srow, base, cnt, bufB, N);
    } else {
        hipMemsetAsync(bufB, 0, (size_t)N * 128 * sizeof(float), stream);
        message_pass<<<mp_blocks_atm, 256, 0, stream>>>(bufA, mq, row, col, bufB, E);
    }

    // Layer 2
    gemm_relu_norm<128, 128, true><<<(N + 15) / 16, 256, 0, stream>>>(bufB, W1, b1, bufA, mq, N);
    if (use_csr) {
        message_pass_csr<<<mp_blocks_csr, 256, 0, stream>>>(bufA, mq, srow, base, cnt, bufB, N);
    } else {
        hipMemsetAsync(bufB, 0, (size_t)N * 128 * sizeof(float), stream);
        message_pass<<<mp_blocks_atm, 256, 0, stream>>>(bufA, mq, row, col, bufB, E);
    }

    // Layer 3: h3 [N,64]
    gemm_relu_norm<128, 64, false><<<(N + 31) / 32, 256, 0, stream>>>(bufB, W2, b2, bufA, nullptr, N);

    // Classifier head
    classifier_kernel<<<(N + 255) / 256, 256, 0, stream>>>(bufA, Wc1, bc1, Wc2, bc2, out, N);
}

// Round 8
// 778.525 us; speedup vs baseline: 2.3338x; 1.1888x over previous
//
#include <hip/hip_runtime.h>
#include <hip/hip_bf16.h>
#include <math.h>

// ---------------------------------------------------------------------------
// UHG GNN forward (R3, resubmitted — rounds 3-7 hit GPU acquisition timeout):
//   - GEMMs register-tiled fp32: block 128xM, thread 8x8 (4x8 for M=64),
//     K chunked by 32, A staged transposed in LDS for b128 fragment reads.
//   - CSR message pass (R2, hardware-validated) unchanged.
// ---------------------------------------------------------------------------

template<int K, int M, bool WANT_MQ>
__global__ __launch_bounds__(256) void gemm_tile_norm(
    const float* __restrict__ A, const float* __restrict__ W,
    const float* __restrict__ bias, float* __restrict__ H,
    float* __restrict__ mqout, int N)
{
    constexpr int BM  = 128;        // rows per block
    constexpr int KB  = 32;         // k-chunk
    constexpr int NTX = M / 8;      // threads across cols (16 or 8)
    constexpr int NTY = 256 / NTX;  // thread-rows (16 or 32)
    constexpr int TR  = BM / NTY;   // rows per thread (8 or 4)
    constexpr int SA  = BM + 4;     // As stride (pad: conflict-free b128 reads)
    constexpr int SW  = M + 4;

    __shared__ float As[KB][SA];    // transposed: As[k][row]
    __shared__ float Ws[KB][SW];    // Ws[k][col]

    const int tid  = threadIdx.x;
    const int tx   = tid % NTX;
    const int ty   = tid / NTX;
    const int row0 = blockIdx.x * BM;

    float acc[TR][8];
    #pragma unroll
    for (int r = 0; r < TR; ++r)
        #pragma unroll
        for (int c = 0; c < 8; ++c) acc[r][c] = 0.f;

    const int sf4 = tid % 8;   // A staging: float4 slot within k-chunk
    const int sr0 = tid / 8;   // A staging: row within 32-row group

    for (int kc = 0; kc < K / KB; ++kc) {
        if (kc) __syncthreads();
        // stage A chunk, transposed (coalesced global float4 reads)
        #pragma unroll
        for (int t = 0; t < 4; ++t) {
            const int r    = t * 32 + sr0;
            const int grow = row0 + r;
            float4 v = {0.f, 0.f, 0.f, 0.f};
            if (grow < N)
                v = *(const float4*)(A + (size_t)grow * K + kc * KB + sf4 * 4);
            As[sf4 * 4 + 0][r] = v.x;
            As[sf4 * 4 + 1][r] = v.y;
            As[sf4 * 4 + 2][r] = v.z;
            As[sf4 * 4 + 3][r] = v.w;
        }
        // stage W chunk (row-major, contiguous)
        #pragma unroll
        for (int t = 0; t < KB * M / 4 / 256; ++t) {
            const int idx = t * 256 + tid;
            const int kk  = idx / (M / 4);
            const int c4  = idx % (M / 4);
            *(float4*)&Ws[kk][c4 * 4] =
                *(const float4*)(W + (size_t)(kc * KB + kk) * M + c4 * 4);
        }
        __syncthreads();

        #pragma unroll 8
        for (int k = 0; k < KB; ++k) {
            const float4 w0 = *(const float4*)&Ws[k][tx * 8];
            const float4 w1 = *(const float4*)&Ws[k][tx * 8 + 4];
            float a[TR];
            #pragma unroll
            for (int rq = 0; rq < TR / 4; ++rq) {
                const float4 av = *(const float4*)&As[k][ty * TR + rq * 4];
                a[rq * 4 + 0] = av.x; a[rq * 4 + 1] = av.y;
                a[rq * 4 + 2] = av.z; a[rq * 4 + 3] = av.w;
            }
            #pragma unroll
            for (int r = 0; r < TR; ++r) {
                acc[r][0] += a[r] * w0.x;
                acc[r][1] += a[r] * w0.y;
                acc[r][2] += a[r] * w0.z;
                acc[r][3] += a[r] * w0.w;
                acc[r][4] += a[r] * w1.x;
                acc[r][5] += a[r] * w1.y;
                acc[r][6] += a[r] * w1.z;
                acc[r][7] += a[r] * w1.w;
            }
        }
    }

    // fused epilogue: bias + relu + row-normalize (+ mq)
    const float4 b0 = *(const float4*)(bias + tx * 8);
    const float4 b1 = *(const float4*)(bias + tx * 8 + 4);

    #pragma unroll
    for (int r = 0; r < TR; ++r) {
        float v[8];
        v[0] = fmaxf(acc[r][0] + b0.x, 0.f);
        v[1] = fmaxf(acc[r][1] + b0.y, 0.f);
        v[2] = fmaxf(acc[r][2] + b0.z, 0.f);
        v[3] = fmaxf(acc[r][3] + b0.w, 0.f);
        v[4] = fmaxf(acc[r][4] + b1.x, 0.f);
        v[5] = fmaxf(acc[r][5] + b1.y, 0.f);
        v[6] = fmaxf(acc[r][6] + b1.z, 0.f);
        v[7] = fmaxf(acc[r][7] + b1.w, 0.f);

        float ss = 0.f;
        #pragma unroll
        for (int c = 0; c < 8; ++c) ss += v[c] * v[c];
        #pragma unroll
        for (int off = 1; off < NTX; off <<= 1) ss += __shfl_xor(ss, off);

        const float inv = 1.f / (sqrtf(ss) + 1e-9f);
        const int row = row0 + ty * TR + r;
        if (row < N) {
            float4 o0 = {v[0] * inv, v[1] * inv, v[2] * inv, v[3] * inv};
            float4 o1 = {v[4] * inv, v[5] * inv, v[6] * inv, v[7] * inv};
            *(float4*)(H + (size_t)row * M + tx * 8)     = o0;
            *(float4*)(H + (size_t)row * M + tx * 8 + 4) = o1;
            if (WANT_MQ && tx == NTX - 1) {
                const float hl = v[7] * inv;
                mqout[row] = ss * inv * inv - 2.f * hl * hl;  // mink(h,h)
            }
        }
    }
}

// ------------------------- CSR build -------------------------

__global__ void hist_kernel(const int* __restrict__ col, int* __restrict__ cnt, int E) {
    const int i = blockIdx.x * blockDim.x + threadIdx.x;
    if (i < E) atomicAdd(&cnt[col[i]], 1);
}

#define SCAN_TPB 256
#define SCAN_VPT 4   // 1024 elems per block

__global__ void scan1_kernel(const int* __restrict__ cnt, int* __restrict__ base,
                             int* __restrict__ bsum, int N) {
    __shared__ int s[SCAN_TPB];
    const int t  = threadIdx.x;
    const int i0 = blockIdx.x * (SCAN_TPB * SCAN_VPT) + t * SCAN_VPT;
    int v[SCAN_VPT]; int tot = 0;
    #pragma unroll
    for (int j = 0; j < SCAN_VPT; ++j) {
        v[j] = (i0 + j < N) ? cnt[i0 + j] : 0;
        tot += v[j];
    }
    s[t] = tot;
    __syncthreads();
    for (int off = 1; off < SCAN_TPB; off <<= 1) {
        const int x = (t >= off) ? s[t - off] : 0;
        __syncthreads();
        s[t] += x;
        __syncthreads();
    }
    const int excl = s[t] - tot;
    if (t == SCAN_TPB - 1) bsum[blockIdx.x] = s[SCAN_TPB - 1];
    int run = excl;
    #pragma unroll
    for (int j = 0; j < SCAN_VPT; ++j) {
        if (i0 + j < N) base[i0 + j] = run;
        run += v[j];
    }
}

__global__ void scan2_kernel(int* __restrict__ bsum, int nb) {
    __shared__ int s[SCAN_TPB];
    const int t = threadIdx.x;
    const int v = (t < nb) ? bsum[t] : 0;
    s[t] = v;
    __syncthreads();
    for (int off = 1; off < SCAN_TPB; off <<= 1) {
        const int x = (t >= off) ? s[t - off] : 0;
        __syncthreads();
        s[t] += x;
        __syncthreads();
    }
    if (t < nb) bsum[t] = s[t] - v;   // exclusive
}

__global__ void scan3_kernel(int* __restrict__ base, const int* __restrict__ bsum,
                             int* __restrict__ cursor, int N) {
    const int i = blockIdx.x * blockDim.x + threadIdx.x;
    if (i < N) {
        const int v = base[i] + bsum[i / (SCAN_TPB * SCAN_VPT)];
        base[i]   = v;
        cursor[i] = v;
    }
}

__global__ void scatter_kernel(const int* __restrict__ row, const int* __restrict__ col,
                               int* __restrict__ cursor, int* __restrict__ srow, int E) {
    const int i = blockIdx.x * blockDim.x + threadIdx.x;
    if (i < E) {
        const int pos = atomicAdd(&cursor[col[i]], 1);
        srow[pos] = row[i];
    }
}

// ------------------------- CSR message pass -------------------------
__global__ __launch_bounds__(256) void message_pass_csr(
    const float* __restrict__ h, const float* __restrict__ mq,
    const int* __restrict__ srow, const int* __restrict__ base,
    const int* __restrict__ cnt, float* __restrict__ agg, int N)
{
    const int node = (int)((blockIdx.x * 256u + threadIdx.x) >> 6);
    if (node >= N) return;
    const int lane = threadIdx.x & 63;
    const int gl   = lane & 15;      // lane within 16-lane group
    const int g    = lane >> 4;      // group 0..3

    const float4* hb = (const float4*)(h + (size_t)node * 128 + gl * 8);
    const float4 b0 = hb[0];
    const float4 b1 = hb[1];
    const float mqc = mq[node];

    const int nb = cnt[node];
    const int st = base[node];

    float4 acc0 = {0.f, 0.f, 0.f, 0.f};
    float4 acc1 = {0.f, 0.f, 0.f, 0.f};

    const int iters = (nb + 3) >> 2;
    for (int t = 0; t < iters; ++t) {
        const int ei  = t * 4 + g;
        const bool act = ei < nb;
        const int e   = st + (act ? ei : 0);
        const int r   = srow[e];
        const float4* ha = (const float4*)(h + (size_t)r * 128 + gl * 8);
        const float4 a0 = ha[0];
        const float4 a1 = ha[1];
        const float mqr = mq[r];

        float p = a0.x*b0.x + a0.y*b0.y + a0.z*b0.z + a0.w*b0.w
                + a1.x*b1.x + a1.y*b1.y + a1.z*b1.z;
        p += (gl == 15) ? -a1.w * b1.w : a1.w * b1.w;   // Minkowski sign
        p += __shfl_xor(p, 1);
        p += __shfl_xor(p, 2);
        p += __shfl_xor(p, 4);
        p += __shfl_xor(p, 8);

        const float denom = mqr * mqc + 1e-9f;
        float q = 1.f - (p * p) / denom;
        q = fmaxf(q, 0.f);
        float w = expf(-sqrtf(q));
        w = act ? w : 0.f;

        acc0.x += a0.x*w; acc0.y += a0.y*w; acc0.z += a0.z*w; acc0.w += a0.w*w;
        acc1.x += a1.x*w; acc1.y += a1.y*w; acc1.z += a1.z*w; acc1.w += a1.w*w;
    }

    #pragma unroll
    for (int off = 16; off < 64; off <<= 1) {
        acc0.x += __shfl_xor(acc0.x, off); acc0.y += __shfl_xor(acc0.y, off);
        acc0.z += __shfl_xor(acc0.z, off); acc0.w += __shfl_xor(acc0.w, off);
        acc1.x += __shfl_xor(acc1.x, off); acc1.y += __shfl_xor(acc1.y, off);
        acc1.z += __shfl_xor(acc1.z, off); acc1.w += __shfl_xor(acc1.w, off);
    }
    if (g == 0) {
        float4* out = (float4*)(agg + (size_t)node * 128 + gl * 8);
        out[0] = acc0;
        out[1] = acc1;
    }
}

// ------------------------- fallback atomic message pass -------------------------
__global__ __launch_bounds__(256) void message_pass(
    const float* __restrict__ h, const float* __restrict__ mq,
    const int* __restrict__ row, const int* __restrict__ col,
    float* __restrict__ agg, int E)
{
    const int wid  = (int)((blockIdx.x * (unsigned)blockDim.x + threadIdx.x) >> 6);
    const int lane = threadIdx.x & 63;
    if (wid >= E) return;

    const int r = row[wid];
    const int c = col[wid];

    const float a0 = h[(size_t)r * 128 + lane];
    const float a1 = h[(size_t)r * 128 + 64 + lane];
    const float b0 = h[(size_t)c * 128 + lane];
    const float b1 = h[(size_t)c * 128 + 64 + lane];

    float p = a0 * b0 + ((lane == 63) ? -a1 * b1 : a1 * b1);
    #pragma unroll
    for (int off = 1; off < 64; off <<= 1) p += __shfl_xor(p, off);

    const float denom = mq[r] * mq[c] + 1e-9f;
    float q = 1.f - (p * p) / denom;
    q = fmaxf(q, 0.f);
    const float w = expf(-sqrtf(q));

    atomicAdd(&agg[(size_t)c * 128 + lane],      a0 * w);
    atomicAdd(&agg[(size_t)c * 128 + 64 + lane], a1 * w);
}

// ------------------------- classifier -------------------------
__global__ __launch_bounds__(256) void classifier_kernel(
    const float* __restrict__ h3, const float* __restrict__ Wc1,
    const float* __restrict__ bc1, const float* __restrict__ Wc2,
    const float* __restrict__ bc2, float* __restrict__ out, int N)
{
    __shared__ float w1[64 * 32];
    __shared__ float w2[32];
    __shared__ float b1s[32];

    const int tid = threadIdx.x;
    for (int i = tid; i < 64 * 32; i += 256) w1[i] = Wc1[i];
    if (tid < 32) { w2[tid] = Wc2[tid]; b1s[tid] = bc1[tid]; }
    __syncthreads();

    const int n = blockIdx.x * 256 + tid;
    if (n >= N) return;

    float t1[32];
    #pragma unroll
    for (int c = 0; c < 32; ++c) t1[c] = b1s[c];

    const float4* hrow = (const float4*)(h3 + (size_t)n * 64);
    #pragma unroll
    for (int k4 = 0; k4 < 16; ++k4) {
        const float4 hv = hrow[k4];
        const int k = k4 * 4;
        #pragma unroll
        for (int c = 0; c < 32; ++c) {
            t1[c] += hv.x * w1[(k + 0) * 32 + c] + hv.y * w1[(k + 1) * 32 + c]
                   + hv.z * w1[(k + 2) * 32 + c] + hv.w * w1[(k + 3) * 32 + c];
        }
    }

    float z = bc2[0];
    #pragma unroll
    for (int c = 0; c < 32; ++c) z += fmaxf(t1[c], 0.f) * w2[c];
    out[n] = 1.f / (1.f + expf(-z));
}

extern "C" void kernel_launch(void* const* d_in, const int* in_sizes, int n_in,
                              void* d_out, int out_size, void* d_ws, size_t ws_size,
                              hipStream_t stream)
{
    const float* x    = (const float*)d_in[0];
    const int*   ei   = (const int*)  d_in[1];
    const float* W_in = (const float*)d_in[2];
    const float* b_in = (const float*)d_in[3];
    const float* W1   = (const float*)d_in[4];
    const float* b1   = (const float*)d_in[5];
    const float* W2   = (const float*)d_in[6];
    const float* b2   = (const float*)d_in[7];
    const float* Wc1  = (const float*)d_in[8];
    const float* bc1  = (const float*)d_in[9];
    const float* Wc2  = (const float*)d_in[10];
    const float* bc2  = (const float*)d_in[11];
    float* out = (float*)d_out;

    const int N = in_sizes[0] / 256;   // 100000
    const int E = in_sizes[1] / 2;     // 1600000
    const int* row = ei;
    const int* col = ei + E;

    float* bufA = (float*)d_ws;                   // [N,128]
    float* bufB = bufA + (size_t)N * 128;         // [N,128]
    float* mq   = bufB + (size_t)N * 128;         // [N]
    int*   cnt  = (int*)(mq + N);                 // [N]
    int*   base = cnt + N;                        // [N]
    int*   cur  = base + N;                       // [N]
    int*   bsum = cur + N;                        // [256]
    int*   srow = bsum + 256;                     // [E]

    const size_t need = ((size_t)N * 257 + (size_t)N * 3 + 256 + (size_t)E) * 4;
    const bool use_csr = ws_size >= need;

    const int scan_blk = (N + SCAN_TPB * SCAN_VPT - 1) / (SCAN_TPB * SCAN_VPT);

    if (use_csr) {
        hipMemsetAsync(cnt, 0, (size_t)N * sizeof(int), stream);
        hist_kernel<<<(E + 255) / 256, 256, 0, stream>>>(col, cnt, E);
        scan1_kernel<<<scan_blk, SCAN_TPB, 0, stream>>>(cnt, base, bsum, N);
        scan2_kernel<<<1, SCAN_TPB, 0, stream>>>(bsum, scan_blk);
        scan3_kernel<<<(N + 255) / 256, 256, 0, stream>>>(base, bsum, cur, N);
        scatter_kernel<<<(E + 255) / 256, 256, 0, stream>>>(row, col, cur, srow, E);
    }

    const int gemm_blk = (N + 127) / 128;
    const int mp_blocks_csr = (N + 3) / 4;
    const int mp_blocks_atm = (E + 3) / 4;

    // Layer 1
    gemm_tile_norm<256, 128, true><<<gemm_blk, 256, 0, stream>>>(x, W_in, b_in, bufA, mq, N);
    if (use_csr) {
        message_pass_csr<<<mp_blocks_csr, 256, 0, stream>>>(bufA, mq, srow, base, cnt, bufB, N);
    } else {
        hipMemsetAsync(bufB, 0, (size_t)N * 128 * sizeof(float), stream);
        message_pass<<<mp_blocks_atm, 256, 0, stream>>>(bufA, mq, row, col, bufB, E);
    }

    // Layer 2
    gemm_tile_norm<128, 128, true><<<gemm_blk, 256, 0, stream>>>(bufB, W1, b1, bufA, mq, N);
    if (use_csr) {
        message_pass_csr<<<mp_blocks_csr, 256, 0, stream>>>(bufA, mq, srow, base, cnt, bufB, N);
    } else {
        hipMemsetAsync(bufB, 0, (size_t)N * 128 * sizeof(float), stream);
        message_pass<<<mp_blocks_atm, 256, 0, stream>>>(bufA, mq, row, col, bufB, E);
    }

    // Layer 3: h3 [N,64]
    gemm_tile_norm<128, 64, false><<<gemm_blk, 256, 0, stream>>>(bufB, W2, b2, bufA, nullptr, N);

    // Classifier head
    classifier_kernel<<<(N + 255) / 256, 256, 0, stream>>>(bufA, Wc1, bc1, Wc2, bc2, out, N);
}